// Round 9
// baseline (277.826 us; speedup 1.0000x reference)
//
#include <hip/hip_runtime.h>
#include <hip/hip_fp16.h>
#include <math.h>

// GCN: out = softmax( S·relu((S·h)W1 + b1) · W2 + b2 ),  S = in-edge sum + self-loop.
// Round 9: round-7 skeleton (last green, 277us) + ONE delta: X stored fp16
// (gemm1 converts on store, gemm2 stages fp16->fp32). Round 8's fused rewrite
// failed the replay-consistency check; reverted.

constexpr int N = 100000;
constexpr int E = 1200000;
constexpr int D = 64;    // input dim
constexpr int H = 128;   // hidden
constexpr int C = 40;    // classes
constexpr int NBUCK2 = 98;                      // buckets of 1024 dst nodes
constexpr int EBLK   = 2048;                    // edges per histo/append block
constexpr int NHB    = (E + EBLK - 1) / EBLK;   // 586 edge blocks

// ---- h (fp32) -> HH (fp16), row = 64 halves = 128 B ----
__global__ __launch_bounds__(256) void convert_h(const float2* __restrict__ hf,
                                                 __half2* __restrict__ HH) {
    int i = (blockIdx.x * 256 + threadIdx.x) * 4;   // N*32 half2, exact
#pragma unroll
    for (int k = 0; k < 4; ++k) {
        float2 p = hf[i + k];
        HH[i + k] = __floats2half2_rn(p.x, p.y);
    }
}

// ---- per-block LDS bucket histogram (98 buckets), dense partial dump ----
__global__ __launch_bounds__(256) void histo_b(const int2* __restrict__ edges,
                                               int* __restrict__ partial) {
    __shared__ int cnt[NBUCK2];
    if (threadIdx.x < NBUCK2) cnt[threadIdx.x] = 0;
    __syncthreads();
    int base = blockIdx.x * EBLK + threadIdx.x * 8;
#pragma unroll
    for (int i = 0; i < 8; ++i) {
        int e = base + i;
        if (e < E) atomicAdd(&cnt[edges[e].y >> 10], 1);
    }
    __syncthreads();
    if (threadIdx.x < NBUCK2)
        partial[blockIdx.x * NBUCK2 + threadIdx.x] = cnt[threadIdx.x];
}

// ---- per-bucket column scan of partial: obase[b][blk], btot[b] ----
__global__ __launch_bounds__(1024) void scan_pb(const int* __restrict__ partial,
                                                int* __restrict__ obase,
                                                int* __restrict__ btot) {
    __shared__ int s[1024];
    int b = blockIdx.x, t = threadIdx.x;
    int v = (t < NHB) ? partial[t * NBUCK2 + b] : 0;
    s[t] = v;
    __syncthreads();
    for (int off = 1; off < 1024; off <<= 1) {
        int x = (t >= off) ? s[t - off] : 0;
        __syncthreads();
        s[t] += x;
        __syncthreads();
    }
    if (t < NHB) obase[b * NHB + t] = s[t] - v;   // exclusive within bucket
    if (t == 1023) btot[b] = s[1023];
}

// ---- exclusive scan of bucket totals -> bstart[0..NBUCK2] ----
__global__ __launch_bounds__(128) void scan_bt(const int* __restrict__ btot,
                                               int* __restrict__ bstart) {
    __shared__ int s[128];
    int t = threadIdx.x;
    int v = (t < NBUCK2) ? btot[t] : 0;
    s[t] = v;
    __syncthreads();
    for (int off = 1; off < 128; off <<= 1) {
        int x = (t >= off) ? s[t - off] : 0;
        __syncthreads();
        s[t] += x;
        __syncthreads();
    }
    if (t < NBUCK2) bstart[t] = s[t] - v;
    if (t == NBUCK2 - 1) bstart[NBUCK2] = s[t];   // = E
}

// ---- append: deterministic positions, LDS cursors seeded from scanned bases ----
__global__ __launch_bounds__(256) void append_b(const int2* __restrict__ edges,
                                                const int* __restrict__ bstart,
                                                const int* __restrict__ obase,
                                                int* __restrict__ staging) {
    __shared__ int cur[NBUCK2];
    int blk = blockIdx.x;
    if (threadIdx.x < NBUCK2)
        cur[threadIdx.x] = bstart[threadIdx.x] + obase[threadIdx.x * NHB + blk];
    __syncthreads();
    int base = blk * EBLK + threadIdx.x * 8;
#pragma unroll
    for (int i = 0; i < 8; ++i) {
        int e = base + i;
        if (e < E) {
            int2 ed = edges[e];
            int b = ed.y >> 10;
            int p = atomicAdd(&cur[b], 1);               // LDS atomic
            staging[p] = (ed.x << 10) | (ed.y & 1023);   // src:17b | dst_local:10b
        }
    }
}

// ---- per-bucket: LDS count + scan -> deg/row_start, scatter csr in window ----
__global__ __launch_bounds__(1024) void fill_b(const int* __restrict__ staging,
                                               const int* __restrict__ bstart,
                                               int* __restrict__ deg,
                                               int* __restrict__ row_start,
                                               int* __restrict__ csr) {
    __shared__ int cnt[1024], s[1024], cur[1024];
    int b = blockIdx.x, t = threadIdx.x;
    cnt[t] = 0;
    __syncthreads();
    int lo = bstart[b], hi = bstart[b + 1];
    for (int i = lo + t; i < hi; i += 1024)
        atomicAdd(&cnt[staging[i] & 1023], 1);
    __syncthreads();
    int v = cnt[t];
    s[t] = v;
    __syncthreads();
    for (int off = 1; off < 1024; off <<= 1) {
        int x = (t >= off) ? s[t - off] : 0;
        __syncthreads();
        s[t] += x;
        __syncthreads();
    }
    int ex = s[t] - v;
    cur[t] = ex;
    int node = (b << 10) + t;
    if (node < N) { deg[node] = v; row_start[node] = lo + ex; }
    __syncthreads();
    for (int i = lo + t; i < hi; i += 1024) {
        int w = staging[i];
        int p = atomicAdd(&cur[w & 1023], 1);
        csr[lo + p] = w >> 10;
    }
}

// ---- layer-1 gather (fp16 rows): two 32-lane groups over alternate edges ----
__global__ __launch_bounds__(256) void gather1(const __half2* __restrict__ HH,
                                               const int* __restrict__ csr,
                                               const int* __restrict__ row_start,
                                               const int* __restrict__ deg,
                                               float2* __restrict__ agg) {
    int node = blockIdx.x * 4 + (threadIdx.x >> 6);
    int lane = threadIdx.x & 63;
    int g  = lane >> 5;        // 0/1
    int fl = lane & 31;        // half2 index: features 2fl, 2fl+1
    int rs = row_start[node], d = deg[node];
    float ax = 0.f, ay = 0.f;
    if (g == 0) {              // self-loop
        float2 v = __half22float2(HH[node * 32 + fl]);
        ax = v.x; ay = v.y;
    }
    int j = g;
    for (; j + 2 < d; j += 4) {
        int i0 = csr[rs + j], i1 = csr[rs + j + 2];
        float2 v0 = __half22float2(HH[i0 * 32 + fl]);
        float2 v1 = __half22float2(HH[i1 * 32 + fl]);
        ax += v0.x + v1.x;
        ay += v0.y + v1.y;
    }
    for (; j < d; j += 2) {
        float2 v = __half22float2(HH[csr[rs + j] * 32 + fl]);
        ax += v.x; ay += v.y;
    }
    ax += __shfl_xor(ax, 32);
    ay += __shfl_xor(ay, 32);
    if (lane < 32) agg[node * 32 + fl] = make_float2(ax, ay);
}

// ---- XH = fp16(relu(agg @ W1 + b1)), tiled ----
__global__ __launch_bounds__(256) void gemm1_relu(const float* __restrict__ A,
                                                  const float* __restrict__ W1,
                                                  const float* __restrict__ b1,
                                                  __half* __restrict__ XH) {
    __shared__ float w_s[D * H];      // 32 KB
    __shared__ float a_s[16 * D];     // 4 KB
    int row0 = blockIdx.x * 16;
    {
        const float4* src = (const float4*)W1;
        float4* dst = (float4*)w_s;
#pragma unroll
        for (int i = 0; i < 8; ++i)
            dst[threadIdx.x + i * 256] = src[threadIdx.x + i * 256];
    }
    {
        int r = threadIdx.x >> 4;
        int q = threadIdx.x & 15;
        float4 v = *(const float4*)&A[(row0 + r) * D + q * 4];
        *(float4*)&a_s[r * D + q * 4] = v;
    }
    __syncthreads();

    int tr   = threadIdx.x >> 6;
    int lane = threadIdx.x & 63;
    float acc[4][2] = {};
#pragma unroll
    for (int k = 0; k < D; ++k) {
        float b0 = w_s[k * H + lane];
        float b1v = w_s[k * H + lane + 64];
#pragma unroll
        for (int i = 0; i < 4; ++i) {
            float a = a_s[(tr + 4 * i) * D + k];
            acc[i][0] = fmaf(a, b0, acc[i][0]);
            acc[i][1] = fmaf(a, b1v, acc[i][1]);
        }
    }
    float bias0 = b1[lane], bias1 = b1[lane + 64];
#pragma unroll
    for (int i = 0; i < 4; ++i) {
        int row = row0 + tr + 4 * i;
        XH[row * H + lane]      = __float2half_rn(fmaxf(acc[i][0] + bias0, 0.f));
        XH[row * H + lane + 64] = __float2half_rn(fmaxf(acc[i][1] + bias1, 0.f));
    }
}

// ---- ZH = fp16(XH @ W2), row stride 64 halves, cols 40..63 zero-filled ----
constexpr int XS = 132;
__global__ __launch_bounds__(256) void gemm2(const __half* __restrict__ XH,
                                             const float* __restrict__ W2,
                                             __half* __restrict__ ZH) {
    __shared__ float w_s[H * C];        // 20 KB
    __shared__ float x_s[64 * XS];      // 33.8 KB
    int row0 = blockIdx.x * 64;
    {
        const float4* src = (const float4*)W2;
        float4* dst = (float4*)w_s;
#pragma unroll
        for (int i = 0; i < 5; ++i)
            dst[threadIdx.x + i * 256] = src[threadIdx.x + i * 256];
    }
    {   // stage XH (fp16) -> x_s (fp32): 64 rows x 16 chunks of 8 halves
#pragma unroll
        for (int i = 0; i < 4; ++i) {
            int idx = threadIdx.x + i * 256;   // 1024 chunks
            int r = idx >> 4;
            int q = idx & 15;
            int grow = row0 + r;
            if (grow >= N) grow = N - 1;
            float4 raw = *(const float4*)&XH[grow * H + q * 8];
            __half2* hp = (__half2*)&raw;
            float2 f0 = __half22float2(hp[0]), f1 = __half22float2(hp[1]);
            float2 f2 = __half22float2(hp[2]), f3 = __half22float2(hp[3]);
            float* dst = &x_s[r * XS + q * 8];
            dst[0] = f0.x; dst[1] = f0.y; dst[2] = f1.x; dst[3] = f1.y;
            dst[4] = f2.x; dst[5] = f2.y; dst[6] = f3.x; dst[7] = f3.y;
        }
    }
    __syncthreads();

    int tc   = threadIdx.x & 7;         // cols tc*5 .. tc*5+4
    int trow = threadIdx.x >> 3;        // rows trow*2, trow*2+1
    float acc[2][5] = {};
#pragma unroll 4
    for (int k = 0; k < H; ++k) {
        float b[5];
#pragma unroll
        for (int j = 0; j < 5; ++j) b[j] = w_s[k * C + tc * 5 + j];
        float a0 = x_s[(trow * 2) * XS + k];
        float a1 = x_s[(trow * 2 + 1) * XS + k];
#pragma unroll
        for (int j = 0; j < 5; ++j) {
            acc[0][j] = fmaf(a0, b[j], acc[0][j]);
            acc[1][j] = fmaf(a1, b[j], acc[1][j]);
        }
    }
#pragma unroll
    for (int i = 0; i < 2; ++i) {
        int row = row0 + trow * 2 + i;
        if (row < N) {
#pragma unroll
            for (int j = 0; j < 5; ++j)
                ZH[row * 64 + tc * 5 + j] = __float2half_rn(acc[i][j]);
#pragma unroll
            for (int j = 0; j < 3; ++j)          // pad cols 40..63
                ZH[row * 64 + 40 + tc * 3 + j] = __half(0.f);
        }
    }
}

// ---- out[node] = softmax(Z[node] + sum Z[src] + b2); three 20-lane groups ----
__global__ __launch_bounds__(256) void gather2_softmax(const __half2* __restrict__ ZH,
                                                       const int* __restrict__ csr,
                                                       const int* __restrict__ row_start,
                                                       const int* __restrict__ deg,
                                                       const float2* __restrict__ b2,
                                                       float2* __restrict__ out) {
    int node = blockIdx.x * 4 + (threadIdx.x >> 6);
    int lane = threadIdx.x & 63;
    int g  = (lane >= 40) ? 2 : (lane >= 20 ? 1 : 0);
    if (lane >= 60) g = 3;                               // inactive
    int fl = lane - g * 20;                              // half2 index
    bool active = (g < 3);
    int rs = row_start[node], d = deg[node];
    float ax = 0.f, ay = 0.f;
    if (g == 0) {                                        // self-loop
        float2 v = __half22float2(ZH[node * 32 + fl]);
        ax = v.x; ay = v.y;
    }
    if (active) {
        int j = g;
        for (; j + 3 < d; j += 6) {
            int i0 = csr[rs + j], i1 = csr[rs + j + 3];
            float2 v0 = __half22float2(ZH[i0 * 32 + fl]);
            float2 v1 = __half22float2(ZH[i1 * 32 + fl]);
            ax += v0.x + v1.x;
            ay += v0.y + v1.y;
        }
        for (; j < d; j += 3) {
            float2 v = __half22float2(ZH[csr[rs + j] * 32 + fl]);
            ax += v.x; ay += v.y;
        }
    }
    ax += __shfl(ax, (lane + 20) & 63) + __shfl(ax, (lane + 40) & 63);
    ay += __shfl(ay, (lane + 20) & 63) + __shfl(ay, (lane + 40) & 63);
    float vx = -INFINITY, vy = -INFINITY;
    if (lane < 20) {
        float2 bbv = b2[lane];
        vx = ax + bbv.x;
        vy = ay + bbv.y;
    }
    float m = fmaxf(vx, vy);
#pragma unroll
    for (int off = 16; off; off >>= 1) m = fmaxf(m, __shfl_xor(m, off));
    float ex = (lane < 20) ? expf(vx - m) : 0.f;
    float ey = (lane < 20) ? expf(vy - m) : 0.f;
    float ssum = ex + ey;
#pragma unroll
    for (int off = 16; off; off >>= 1) ssum += __shfl_xor(ssum, off);
    if (lane < 20) {
        float inv = 1.f / ssum;
        out[node * 20 + lane] = make_float2(ex * inv, ey * inv);
    }
}

extern "C" void kernel_launch(void* const* d_in, const int* in_sizes, int n_in,
                              void* d_out, int out_size, void* d_ws, size_t ws_size,
                              hipStream_t stream) {
    const float* h   = (const float*)d_in[0];   // N*D
    const int*   adj = (const int*)  d_in[1];   // E*2
    const float* W1  = (const float*)d_in[2];   // D*H
    const float* b1  = (const float*)d_in[3];   // H
    const float* W2  = (const float*)d_in[4];   // H*C
    const float* b2  = (const float*)d_in[5];   // C
    float* out = (float*)d_out;                 // N*C fp32

    // workspace (~87.7 MB), NO aliasing:
    //   agg1 fp32 N*64 | HH fp16 N*64 | XH fp16 N*128 | ZH fp16 N*64 | ints
    float*  agg1 = (float*)d_ws;                        // N*64 fp32
    __half* HH   = (__half*)(agg1 + (size_t)N * 64);    // N*64 fp16
    __half* XH   = HH + (size_t)N * 64;                 // N*128 fp16
    __half* ZH   = XH + (size_t)N * H;                  // N*64 fp16
    int* partial   = (int*)(ZH + (size_t)N * 64);       // NHB*NBUCK2
    int* obase     = partial + NHB * NBUCK2;            // NBUCK2*NHB
    int* btot      = obase + NBUCK2 * NHB;              // 128
    int* bstart    = btot + 128;                        // NBUCK2+1 (pad 128)
    int* staging   = bstart + 128;                      // E
    int* csr       = staging + E;                       // E
    int* deg       = csr + E;                           // N
    int* row_start = deg + N;                           // N

    convert_h<<<N * 32 / (256 * 4), 256, 0, stream>>>((const float2*)h, (__half2*)HH);
    histo_b  <<<NHB, 256, 0, stream>>>((const int2*)adj, partial);
    scan_pb  <<<NBUCK2, 1024, 0, stream>>>(partial, obase, btot);
    scan_bt  <<<1, 128, 0, stream>>>(btot, bstart);
    append_b <<<NHB, 256, 0, stream>>>((const int2*)adj, bstart, obase, staging);
    fill_b   <<<NBUCK2, 1024, 0, stream>>>(staging, bstart, deg, row_start, csr);

    gather1        <<<N / 4, 256, 0, stream>>>((const __half2*)HH, csr, row_start, deg,
                                               (float2*)agg1);
    gemm1_relu     <<<N / 16, 256, 0, stream>>>(agg1, W1, b1, XH);
    gemm2          <<<(N + 63) / 64, 256, 0, stream>>>(XH, W2, ZH);
    gather2_softmax<<<N / 4, 256, 0, stream>>>((const __half2*)ZH, csr, row_start, deg,
                                               (const float2*)b2, (float2*)out);
}

// Round 10
// 272.462 us; speedup vs baseline: 1.0197x; 1.0197x over previous
//
#include <hip/hip_runtime.h>
#include <hip/hip_fp16.h>
#include <math.h>

// GCN: out = softmax( S·relu((S·h)W1 + b1) · W2 + b2 ),  S = in-edge sum + self-loop.
// Round 10: round-9 skeleton (green, 277.8us) + ONE delta: both gathers deepened to
// 4 row-loads in flight per lane group (they are serial-latency bound: ~500cyc L3
// round per 2-deep batch; batch-4 halves the dependent rounds per node).

constexpr int N = 100000;
constexpr int E = 1200000;
constexpr int D = 64;    // input dim
constexpr int H = 128;   // hidden
constexpr int C = 40;    // classes
constexpr int NBUCK2 = 98;                      // buckets of 1024 dst nodes
constexpr int EBLK   = 2048;                    // edges per histo/append block
constexpr int NHB    = (E + EBLK - 1) / EBLK;   // 586 edge blocks

// ---- h (fp32) -> HH (fp16), row = 64 halves = 128 B ----
__global__ __launch_bounds__(256) void convert_h(const float2* __restrict__ hf,
                                                 __half2* __restrict__ HH) {
    int i = (blockIdx.x * 256 + threadIdx.x) * 4;   // N*32 half2, exact
#pragma unroll
    for (int k = 0; k < 4; ++k) {
        float2 p = hf[i + k];
        HH[i + k] = __floats2half2_rn(p.x, p.y);
    }
}

// ---- per-block LDS bucket histogram (98 buckets), dense partial dump ----
__global__ __launch_bounds__(256) void histo_b(const int2* __restrict__ edges,
                                               int* __restrict__ partial) {
    __shared__ int cnt[NBUCK2];
    if (threadIdx.x < NBUCK2) cnt[threadIdx.x] = 0;
    __syncthreads();
    int base = blockIdx.x * EBLK + threadIdx.x * 8;
#pragma unroll
    for (int i = 0; i < 8; ++i) {
        int e = base + i;
        if (e < E) atomicAdd(&cnt[edges[e].y >> 10], 1);
    }
    __syncthreads();
    if (threadIdx.x < NBUCK2)
        partial[blockIdx.x * NBUCK2 + threadIdx.x] = cnt[threadIdx.x];
}

// ---- per-bucket column scan of partial: obase[b][blk], btot[b] ----
__global__ __launch_bounds__(1024) void scan_pb(const int* __restrict__ partial,
                                                int* __restrict__ obase,
                                                int* __restrict__ btot) {
    __shared__ int s[1024];
    int b = blockIdx.x, t = threadIdx.x;
    int v = (t < NHB) ? partial[t * NBUCK2 + b] : 0;
    s[t] = v;
    __syncthreads();
    for (int off = 1; off < 1024; off <<= 1) {
        int x = (t >= off) ? s[t - off] : 0;
        __syncthreads();
        s[t] += x;
        __syncthreads();
    }
    if (t < NHB) obase[b * NHB + t] = s[t] - v;   // exclusive within bucket
    if (t == 1023) btot[b] = s[1023];
}

// ---- exclusive scan of bucket totals -> bstart[0..NBUCK2] ----
__global__ __launch_bounds__(128) void scan_bt(const int* __restrict__ btot,
                                               int* __restrict__ bstart) {
    __shared__ int s[128];
    int t = threadIdx.x;
    int v = (t < NBUCK2) ? btot[t] : 0;
    s[t] = v;
    __syncthreads();
    for (int off = 1; off < 128; off <<= 1) {
        int x = (t >= off) ? s[t - off] : 0;
        __syncthreads();
        s[t] += x;
        __syncthreads();
    }
    if (t < NBUCK2) bstart[t] = s[t] - v;
    if (t == NBUCK2 - 1) bstart[NBUCK2] = s[t];   // = E
}

// ---- append: deterministic positions, LDS cursors seeded from scanned bases ----
__global__ __launch_bounds__(256) void append_b(const int2* __restrict__ edges,
                                                const int* __restrict__ bstart,
                                                const int* __restrict__ obase,
                                                int* __restrict__ staging) {
    __shared__ int cur[NBUCK2];
    int blk = blockIdx.x;
    if (threadIdx.x < NBUCK2)
        cur[threadIdx.x] = bstart[threadIdx.x] + obase[threadIdx.x * NHB + blk];
    __syncthreads();
    int base = blk * EBLK + threadIdx.x * 8;
#pragma unroll
    for (int i = 0; i < 8; ++i) {
        int e = base + i;
        if (e < E) {
            int2 ed = edges[e];
            int b = ed.y >> 10;
            int p = atomicAdd(&cur[b], 1);               // LDS atomic
            staging[p] = (ed.x << 10) | (ed.y & 1023);   // src:17b | dst_local:10b
        }
    }
}

// ---- per-bucket: LDS count + scan -> deg/row_start, scatter csr in window ----
__global__ __launch_bounds__(1024) void fill_b(const int* __restrict__ staging,
                                               const int* __restrict__ bstart,
                                               int* __restrict__ deg,
                                               int* __restrict__ row_start,
                                               int* __restrict__ csr) {
    __shared__ int cnt[1024], s[1024], cur[1024];
    int b = blockIdx.x, t = threadIdx.x;
    cnt[t] = 0;
    __syncthreads();
    int lo = bstart[b], hi = bstart[b + 1];
    for (int i = lo + t; i < hi; i += 1024)
        atomicAdd(&cnt[staging[i] & 1023], 1);
    __syncthreads();
    int v = cnt[t];
    s[t] = v;
    __syncthreads();
    for (int off = 1; off < 1024; off <<= 1) {
        int x = (t >= off) ? s[t - off] : 0;
        __syncthreads();
        s[t] += x;
        __syncthreads();
    }
    int ex = s[t] - v;
    cur[t] = ex;
    int node = (b << 10) + t;
    if (node < N) { deg[node] = v; row_start[node] = lo + ex; }
    __syncthreads();
    for (int i = lo + t; i < hi; i += 1024) {
        int w = staging[i];
        int p = atomicAdd(&cur[w & 1023], 1);
        csr[lo + p] = w >> 10;
    }
}

// ---- layer-1 gather (fp16 rows): two 32-lane groups, 4 rows in flight ----
__global__ __launch_bounds__(256) void gather1(const __half2* __restrict__ HH,
                                               const int* __restrict__ csr,
                                               const int* __restrict__ row_start,
                                               const int* __restrict__ deg,
                                               float2* __restrict__ agg) {
    int node = blockIdx.x * 4 + (threadIdx.x >> 6);
    int lane = threadIdx.x & 63;
    int g  = lane >> 5;        // 0/1: even/odd edges
    int fl = lane & 31;        // half2 index: features 2fl, 2fl+1
    int rs = row_start[node], d = deg[node];
    float ax = 0.f, ay = 0.f;
    if (g == 0) {              // self-loop
        float2 v = __half22float2(HH[node * 32 + fl]);
        ax = v.x; ay = v.y;
    }
    int j = g;
    for (; j + 6 < d; j += 8) {            // 4 rows in flight
        int i0 = csr[rs + j],     i1 = csr[rs + j + 2];
        int i2 = csr[rs + j + 4], i3 = csr[rs + j + 6];
        __half2 r0 = HH[i0 * 32 + fl];
        __half2 r1 = HH[i1 * 32 + fl];
        __half2 r2 = HH[i2 * 32 + fl];
        __half2 r3 = HH[i3 * 32 + fl];
        float2 v0 = __half22float2(r0), v1 = __half22float2(r1);
        float2 v2 = __half22float2(r2), v3 = __half22float2(r3);
        ax += (v0.x + v1.x) + (v2.x + v3.x);
        ay += (v0.y + v1.y) + (v2.y + v3.y);
    }
    for (; j < d; j += 2) {
        float2 v = __half22float2(HH[csr[rs + j] * 32 + fl]);
        ax += v.x; ay += v.y;
    }
    ax += __shfl_xor(ax, 32);
    ay += __shfl_xor(ay, 32);
    if (lane < 32) agg[node * 32 + fl] = make_float2(ax, ay);
}

// ---- XH = fp16(relu(agg @ W1 + b1)), tiled ----
__global__ __launch_bounds__(256) void gemm1_relu(const float* __restrict__ A,
                                                  const float* __restrict__ W1,
                                                  const float* __restrict__ b1,
                                                  __half* __restrict__ XH) {
    __shared__ float w_s[D * H];      // 32 KB
    __shared__ float a_s[16 * D];     // 4 KB
    int row0 = blockIdx.x * 16;
    {
        const float4* src = (const float4*)W1;
        float4* dst = (float4*)w_s;
#pragma unroll
        for (int i = 0; i < 8; ++i)
            dst[threadIdx.x + i * 256] = src[threadIdx.x + i * 256];
    }
    {
        int r = threadIdx.x >> 4;
        int q = threadIdx.x & 15;
        float4 v = *(const float4*)&A[(row0 + r) * D + q * 4];
        *(float4*)&a_s[r * D + q * 4] = v;
    }
    __syncthreads();

    int tr   = threadIdx.x >> 6;
    int lane = threadIdx.x & 63;
    float acc[4][2] = {};
#pragma unroll
    for (int k = 0; k < D; ++k) {
        float b0 = w_s[k * H + lane];
        float b1v = w_s[k * H + lane + 64];
#pragma unroll
        for (int i = 0; i < 4; ++i) {
            float a = a_s[(tr + 4 * i) * D + k];
            acc[i][0] = fmaf(a, b0, acc[i][0]);
            acc[i][1] = fmaf(a, b1v, acc[i][1]);
        }
    }
    float bias0 = b1[lane], bias1 = b1[lane + 64];
#pragma unroll
    for (int i = 0; i < 4; ++i) {
        int row = row0 + tr + 4 * i;
        XH[row * H + lane]      = __float2half_rn(fmaxf(acc[i][0] + bias0, 0.f));
        XH[row * H + lane + 64] = __float2half_rn(fmaxf(acc[i][1] + bias1, 0.f));
    }
}

// ---- ZH = fp16(XH @ W2), row stride 64 halves, cols 40..63 zero-filled ----
constexpr int XS = 132;
__global__ __launch_bounds__(256) void gemm2(const __half* __restrict__ XH,
                                             const float* __restrict__ W2,
                                             __half* __restrict__ ZH) {
    __shared__ float w_s[H * C];        // 20 KB
    __shared__ float x_s[64 * XS];      // 33.8 KB
    int row0 = blockIdx.x * 64;
    {
        const float4* src = (const float4*)W2;
        float4* dst = (float4*)w_s;
#pragma unroll
        for (int i = 0; i < 5; ++i)
            dst[threadIdx.x + i * 256] = src[threadIdx.x + i * 256];
    }
    {   // stage XH (fp16) -> x_s (fp32): 64 rows x 16 chunks of 8 halves
#pragma unroll
        for (int i = 0; i < 4; ++i) {
            int idx = threadIdx.x + i * 256;   // 1024 chunks
            int r = idx >> 4;
            int q = idx & 15;
            int grow = row0 + r;
            if (grow >= N) grow = N - 1;
            float4 raw = *(const float4*)&XH[grow * H + q * 8];
            __half2* hp = (__half2*)&raw;
            float2 f0 = __half22float2(hp[0]), f1 = __half22float2(hp[1]);
            float2 f2 = __half22float2(hp[2]), f3 = __half22float2(hp[3]);
            float* dst = &x_s[r * XS + q * 8];
            dst[0] = f0.x; dst[1] = f0.y; dst[2] = f1.x; dst[3] = f1.y;
            dst[4] = f2.x; dst[5] = f2.y; dst[6] = f3.x; dst[7] = f3.y;
        }
    }
    __syncthreads();

    int tc   = threadIdx.x & 7;         // cols tc*5 .. tc*5+4
    int trow = threadIdx.x >> 3;        // rows trow*2, trow*2+1
    float acc[2][5] = {};
#pragma unroll 4
    for (int k = 0; k < H; ++k) {
        float b[5];
#pragma unroll
        for (int j = 0; j < 5; ++j) b[j] = w_s[k * C + tc * 5 + j];
        float a0 = x_s[(trow * 2) * XS + k];
        float a1 = x_s[(trow * 2 + 1) * XS + k];
#pragma unroll
        for (int j = 0; j < 5; ++j) {
            acc[0][j] = fmaf(a0, b[j], acc[0][j]);
            acc[1][j] = fmaf(a1, b[j], acc[1][j]);
        }
    }
#pragma unroll
    for (int i = 0; i < 2; ++i) {
        int row = row0 + trow * 2 + i;
        if (row < N) {
#pragma unroll
            for (int j = 0; j < 5; ++j)
                ZH[row * 64 + tc * 5 + j] = __float2half_rn(acc[i][j]);
#pragma unroll
            for (int j = 0; j < 3; ++j)          // pad cols 40..63
                ZH[row * 64 + 40 + tc * 3 + j] = __half(0.f);
        }
    }
}

// ---- out[node] = softmax(Z[node] + sum Z[src] + b2); 3x20 lanes, 4 rows in flight ----
__global__ __launch_bounds__(256) void gather2_softmax(const __half2* __restrict__ ZH,
                                                       const int* __restrict__ csr,
                                                       const int* __restrict__ row_start,
                                                       const int* __restrict__ deg,
                                                       const float2* __restrict__ b2,
                                                       float2* __restrict__ out) {
    int node = blockIdx.x * 4 + (threadIdx.x >> 6);
    int lane = threadIdx.x & 63;
    int g  = (lane >= 40) ? 2 : (lane >= 20 ? 1 : 0);
    if (lane >= 60) g = 3;                               // inactive
    int fl = lane - g * 20;                              // half2 index
    bool active = (g < 3);
    int rs = row_start[node], d = deg[node];
    float ax = 0.f, ay = 0.f;
    if (g == 0) {                                        // self-loop
        float2 v = __half22float2(ZH[node * 32 + fl]);
        ax = v.x; ay = v.y;
    }
    if (active) {
        int j = g;
        for (; j + 9 < d; j += 12) {       // 4 rows in flight
            int i0 = csr[rs + j],     i1 = csr[rs + j + 3];
            int i2 = csr[rs + j + 6], i3 = csr[rs + j + 9];
            __half2 r0 = ZH[i0 * 32 + fl];
            __half2 r1 = ZH[i1 * 32 + fl];
            __half2 r2 = ZH[i2 * 32 + fl];
            __half2 r3 = ZH[i3 * 32 + fl];
            float2 v0 = __half22float2(r0), v1 = __half22float2(r1);
            float2 v2 = __half22float2(r2), v3 = __half22float2(r3);
            ax += (v0.x + v1.x) + (v2.x + v3.x);
            ay += (v0.y + v1.y) + (v2.y + v3.y);
        }
        for (; j < d; j += 3) {
            float2 v = __half22float2(ZH[csr[rs + j] * 32 + fl]);
            ax += v.x; ay += v.y;
        }
    }
    ax += __shfl(ax, (lane + 20) & 63) + __shfl(ax, (lane + 40) & 63);
    ay += __shfl(ay, (lane + 20) & 63) + __shfl(ay, (lane + 40) & 63);
    float vx = -INFINITY, vy = -INFINITY;
    if (lane < 20) {
        float2 bbv = b2[lane];
        vx = ax + bbv.x;
        vy = ay + bbv.y;
    }
    float m = fmaxf(vx, vy);
#pragma unroll
    for (int off = 16; off; off >>= 1) m = fmaxf(m, __shfl_xor(m, off));
    float ex = (lane < 20) ? expf(vx - m) : 0.f;
    float ey = (lane < 20) ? expf(vy - m) : 0.f;
    float ssum = ex + ey;
#pragma unroll
    for (int off = 16; off; off >>= 1) ssum += __shfl_xor(ssum, off);
    if (lane < 20) {
        float inv = 1.f / ssum;
        out[node * 20 + lane] = make_float2(ex * inv, ey * inv);
    }
}

extern "C" void kernel_launch(void* const* d_in, const int* in_sizes, int n_in,
                              void* d_out, int out_size, void* d_ws, size_t ws_size,
                              hipStream_t stream) {
    const float* h   = (const float*)d_in[0];   // N*D
    const int*   adj = (const int*)  d_in[1];   // E*2
    const float* W1  = (const float*)d_in[2];   // D*H
    const float* b1  = (const float*)d_in[3];   // H
    const float* W2  = (const float*)d_in[4];   // H*C
    const float* b2  = (const float*)d_in[5];   // C
    float* out = (float*)d_out;                 // N*C fp32

    // workspace (~87.7 MB), NO aliasing:
    //   agg1 fp32 N*64 | HH fp16 N*64 | XH fp16 N*128 | ZH fp16 N*64 | ints
    float*  agg1 = (float*)d_ws;                        // N*64 fp32
    __half* HH   = (__half*)(agg1 + (size_t)N * 64);    // N*64 fp16
    __half* XH   = HH + (size_t)N * 64;                 // N*128 fp16
    __half* ZH   = XH + (size_t)N * H;                  // N*64 fp16
    int* partial   = (int*)(ZH + (size_t)N * 64);       // NHB*NBUCK2
    int* obase     = partial + NHB * NBUCK2;            // NBUCK2*NHB
    int* btot      = obase + NBUCK2 * NHB;              // 128
    int* bstart    = btot + 128;                        // NBUCK2+1 (pad 128)
    int* staging   = bstart + 128;                      // E
    int* csr       = staging + E;                       // E
    int* deg       = csr + E;                           // N
    int* row_start = deg + N;                           // N

    convert_h<<<N * 32 / (256 * 4), 256, 0, stream>>>((const float2*)h, (__half2*)HH);
    histo_b  <<<NHB, 256, 0, stream>>>((const int2*)adj, partial);
    scan_pb  <<<NBUCK2, 1024, 0, stream>>>(partial, obase, btot);
    scan_bt  <<<1, 128, 0, stream>>>(btot, bstart);
    append_b <<<NHB, 256, 0, stream>>>((const int2*)adj, bstart, obase, staging);
    fill_b   <<<NBUCK2, 1024, 0, stream>>>(staging, bstart, deg, row_start, csr);

    gather1        <<<N / 4, 256, 0, stream>>>((const __half2*)HH, csr, row_start, deg,
                                               (float2*)agg1);
    gemm1_relu     <<<N / 16, 256, 0, stream>>>(agg1, W1, b1, XH);
    gemm2          <<<(N + 63) / 64, 256, 0, stream>>>(XH, W2, ZH);
    gather2_softmax<<<N / 4, 256, 0, stream>>>((const __half2*)ZH, csr, row_start, deg,
                                               (const float2*)b2, (float2*)out);
}